// Round 1
// baseline (1093.515 us; speedup 1.0000x reference)
//
#include <hip/hip_runtime.h>

#define NCLS 19
#define NBINS 20        // +1 trash bin so any out-of-range label is harmless
#define NCH 256
#define NPIX 65536      // 256*256
#define NBATCH 4
#define TPB 256
#define EPSV 1e-5f
#define CNT_THRESH 6

// One kernel: per-(batch, channel-pair) block streams x (2 channels) + y once,
// accumulating per-class {sum_a, sum_b, sumsq_a, sumsq_b, count} into
// label-indexed LDS bins with ds_add_f32 (no 19-way compare ladder).
//
// LDS layout bins[cls][comp][lane]: word index = cls*320 + comp*64 + lane.
// 320 and 64 are both 0 mod 32, so bank = lane mod 32 for every lane of a
// wave regardless of its label -> only the free 2-way conflict, and never a
// same-address collision within one wave instruction.
__global__ __launch_bounds__(TPB) void moment_kernel(const float* __restrict__ x,
                                                     const int* __restrict__ y,
                                                     float* __restrict__ out) {
    const int tid = threadIdx.x, lane = tid & 63, w = tid >> 6;
    const int cp = blockIdx.x;          // channels 2cp, 2cp+1
    const int b  = blockIdx.y;

    __shared__ float bins[NBINS][5][64];   // 25.6 KB
    float* bf = &bins[0][0][0];
    #pragma unroll
    for (int i = tid; i < NBINS * 5 * 64; i += TPB) bf[i] = 0.f;
    __syncthreads();

    const float4* xa = (const float4*)(x + ((size_t)(b * NCH + 2 * cp)) * NPIX);
    const float4* xb = xa + NPIX / 4;
    const int4*   yp = (const int4*)(y + (size_t)b * NPIX);

    #pragma unroll 4
    for (int it = tid; it < NPIX / 4; it += TPB) {   // 64 iterations/thread
        float4 va = xa[it];
        float4 vb = xb[it];
        int4   l  = yp[it];
        {
            unsigned c = min((unsigned)l.x, (unsigned)NCLS);
            float* p = &bins[c][0][lane];
            atomicAdd(p,       va.x);        atomicAdd(p + 64,  vb.x);
            atomicAdd(p + 128, va.x * va.x); atomicAdd(p + 192, vb.x * vb.x);
            atomicAdd(p + 256, 1.0f);
        }
        {
            unsigned c = min((unsigned)l.y, (unsigned)NCLS);
            float* p = &bins[c][0][lane];
            atomicAdd(p,       va.y);        atomicAdd(p + 64,  vb.y);
            atomicAdd(p + 128, va.y * va.y); atomicAdd(p + 192, vb.y * vb.y);
            atomicAdd(p + 256, 1.0f);
        }
        {
            unsigned c = min((unsigned)l.z, (unsigned)NCLS);
            float* p = &bins[c][0][lane];
            atomicAdd(p,       va.z);        atomicAdd(p + 64,  vb.z);
            atomicAdd(p + 128, va.z * va.z); atomicAdd(p + 192, vb.z * vb.z);
            atomicAdd(p + 256, 1.0f);
        }
        {
            unsigned c = min((unsigned)l.w, (unsigned)NCLS);
            float* p = &bins[c][0][lane];
            atomicAdd(p,       va.w);        atomicAdd(p + 64,  vb.w);
            atomicAdd(p + 128, va.w * va.w); atomicAdd(p + 192, vb.w * vb.w);
            atomicAdd(p + 256, 1.0f);
        }
    }
    __syncthreads();

    // Cross-lane reduction: wave w handles classes {w, w+4, ...}.
    // bins[k][comp][lane] read at bank = lane mod 32 (2-way, free).
    for (int k = w; k < NCLS; k += 4) {
        float sa = bins[k][0][lane], sb = bins[k][1][lane],
              qa = bins[k][2][lane], qb = bins[k][3][lane],
              cn = bins[k][4][lane];
        #pragma unroll
        for (int off = 32; off; off >>= 1) {
            sa += __shfl_down(sa, off);
            sb += __shfl_down(sb, off);
            qa += __shfl_down(qa, off);
            qb += __shfl_down(qb, off);
            cn += __shfl_down(cn, off);
        }
        if (lane == 0) {
            const float nf   = cn;                      // exact (<= 65536)
            const bool  valid = nf > (float)CNT_THRESH;
            const float inv  = 1.0f / fmaxf(nf, 1.0f);
            const float dinv = 1.0f / fmaxf(nf - 1.0f, 1.0f);
            const float ma = sa * inv, mb = sb * inv;
            const float vara = fmaxf((qa - nf * ma * ma) * dinv, 0.0f);
            const float varb = fmaxf((qb - nf * mb * mb) * dinv, 0.0f);
            const int oa = (b * NCLS + k) * NCH + 2 * cp;
            out[oa]     = valid ? ma : 0.0f;
            out[oa + 1] = valid ? mb : 0.0f;
            out[NBATCH * NCLS * NCH + oa]     = valid ? (sqrtf(vara) + EPSV) : 0.0f;
            out[NBATCH * NCLS * NCH + oa + 1] = valid ? (sqrtf(varb) + EPSV) : 0.0f;
            if (cp == 0)
                out[2 * NBATCH * NCLS * NCH + b * NCLS + k] = valid ? 1.0f : 0.0f;
        }
    }
}

extern "C" void kernel_launch(void* const* d_in, const int* in_sizes, int n_in,
                              void* d_out, int out_size, void* d_ws, size_t ws_size,
                              hipStream_t stream) {
    const float* x = (const float*)d_in[0];
    const int*   y = (const int*)d_in[1];
    float* out = (float*)d_out;
    (void)d_ws; (void)ws_size;

    dim3 grid(NCH / 2, NBATCH);
    moment_kernel<<<grid, TPB, 0, stream>>>(x, y, out);
}

// Round 2
// 1093.185 us; speedup vs baseline: 1.0003x; 1.0003x over previous
//
#include <hip/hip_runtime.h>

#define NCLS 19
#define NBINS 20        // +1 trash bin so any out-of-range label is harmless
#define NCH 256
#define NPIX 65536      // 256*256
#define NBATCH 4
#define TPB 256
#define EPSV 1e-5f
#define CNT_THRESH 6

// Per-(batch, channel-pair) block streams x (2 channels) + y once, scattering
// per-class {sum_a, sum_b, sumsq_a, sumsq_b, count} into label-indexed LDS
// bins. KEY CHANGE vs round 1: unsafeAtomicAdd -> native fire-and-forget
// ds_add_f32 (round 1's atomicAdd(float*) lowered to a CAS retry loop at
// ~197 cyc/op; the native op is ~2-6 cyc and returns nothing, so there is
// no dependency chain to stall on).
//
// LDS layout bins[cls][comp][lane]: word index = cls*320 + comp*64 + lane.
// 320 % 32 == 0 and 64 % 32 == 0, so bank = lane mod 32 for every lane
// regardless of label -> only the free 2-way wave64 aliasing, and never a
// same-address collision within one wave instruction (lane owns its column).
__global__ __launch_bounds__(TPB) void moment_kernel(const float* __restrict__ x,
                                                     const int* __restrict__ y,
                                                     float* __restrict__ out) {
    const int tid = threadIdx.x, lane = tid & 63, w = tid >> 6;
    const int cp = blockIdx.x;          // channels 2cp, 2cp+1
    const int b  = blockIdx.y;

    __shared__ float bins[NBINS][5][64];   // 25.6 KB
    float* bf = &bins[0][0][0];
    #pragma unroll
    for (int i = tid; i < NBINS * 5 * 64; i += TPB) bf[i] = 0.f;
    __syncthreads();

    const float4* xa = (const float4*)(x + ((size_t)(b * NCH + 2 * cp)) * NPIX);
    const float4* xb = xa + NPIX / 4;
    const int4*   yp = (const int4*)(y + (size_t)b * NPIX);

    #pragma unroll 2
    for (int it = tid; it < NPIX / 4; it += TPB) {   // 64 iterations/thread
        float4 va = xa[it];
        float4 vb = xb[it];
        int4   l  = yp[it];
        {
            unsigned c = min((unsigned)l.x, (unsigned)NCLS);
            float* p = &bins[c][0][lane];
            unsafeAtomicAdd(p,       va.x);        unsafeAtomicAdd(p + 64,  vb.x);
            unsafeAtomicAdd(p + 128, va.x * va.x); unsafeAtomicAdd(p + 192, vb.x * vb.x);
            unsafeAtomicAdd(p + 256, 1.0f);
        }
        {
            unsigned c = min((unsigned)l.y, (unsigned)NCLS);
            float* p = &bins[c][0][lane];
            unsafeAtomicAdd(p,       va.y);        unsafeAtomicAdd(p + 64,  vb.y);
            unsafeAtomicAdd(p + 128, va.y * va.y); unsafeAtomicAdd(p + 192, vb.y * vb.y);
            unsafeAtomicAdd(p + 256, 1.0f);
        }
        {
            unsigned c = min((unsigned)l.z, (unsigned)NCLS);
            float* p = &bins[c][0][lane];
            unsafeAtomicAdd(p,       va.z);        unsafeAtomicAdd(p + 64,  vb.z);
            unsafeAtomicAdd(p + 128, va.z * va.z); unsafeAtomicAdd(p + 192, vb.z * vb.z);
            unsafeAtomicAdd(p + 256, 1.0f);
        }
        {
            unsigned c = min((unsigned)l.w, (unsigned)NCLS);
            float* p = &bins[c][0][lane];
            unsafeAtomicAdd(p,       va.w);        unsafeAtomicAdd(p + 64,  vb.w);
            unsafeAtomicAdd(p + 128, va.w * va.w); unsafeAtomicAdd(p + 192, vb.w * vb.w);
            unsafeAtomicAdd(p + 256, 1.0f);
        }
    }
    __syncthreads();   // emits s_waitcnt lgkmcnt(0) before s_barrier -> all ds_adds landed

    // Cross-lane reduction: wave w handles classes {w, w+4, ...}.
    for (int k = w; k < NCLS; k += 4) {
        float sa = bins[k][0][lane], sb = bins[k][1][lane],
              qa = bins[k][2][lane], qb = bins[k][3][lane],
              cn = bins[k][4][lane];
        #pragma unroll
        for (int off = 32; off; off >>= 1) {
            sa += __shfl_down(sa, off);
            sb += __shfl_down(sb, off);
            qa += __shfl_down(qa, off);
            qb += __shfl_down(qb, off);
            cn += __shfl_down(cn, off);
        }
        if (lane == 0) {
            const float nf   = cn;                      // exact (<= 65536 < 2^24)
            const bool  valid = nf > (float)CNT_THRESH;
            const float inv  = 1.0f / fmaxf(nf, 1.0f);
            const float dinv = 1.0f / fmaxf(nf - 1.0f, 1.0f);
            const float ma = sa * inv, mb = sb * inv;
            const float vara = fmaxf((qa - nf * ma * ma) * dinv, 0.0f);
            const float varb = fmaxf((qb - nf * mb * mb) * dinv, 0.0f);
            const int oa = (b * NCLS + k) * NCH + 2 * cp;
            out[oa]     = valid ? ma : 0.0f;
            out[oa + 1] = valid ? mb : 0.0f;
            out[NBATCH * NCLS * NCH + oa]     = valid ? (sqrtf(vara) + EPSV) : 0.0f;
            out[NBATCH * NCLS * NCH + oa + 1] = valid ? (sqrtf(varb) + EPSV) : 0.0f;
            if (cp == 0)
                out[2 * NBATCH * NCLS * NCH + b * NCLS + k] = valid ? 1.0f : 0.0f;
        }
    }
}

extern "C" void kernel_launch(void* const* d_in, const int* in_sizes, int n_in,
                              void* d_out, int out_size, void* d_ws, size_t ws_size,
                              hipStream_t stream) {
    const float* x = (const float*)d_in[0];
    const int*   y = (const int*)d_in[1];
    float* out = (float*)d_out;
    (void)d_ws; (void)ws_size;

    dim3 grid(NCH / 2, NBATCH);
    moment_kernel<<<grid, TPB, 0, stream>>>(x, y, out);
}